// Round 1
// baseline (1812.077 us; speedup 1.0000x reference)
//
#include <hip/hip_runtime.h>

// ---------------------------------------------------------------------------
// 2-layer ReLU RNN (B=64,T=512,I=256,H=512) + FC(512->1) + sigmoid. fp32 I/O.
// Round 10: single-barrier scan steps via double-buffered hbuf.
//   blocks  0-15: gemm0 (g,s): xw0 = x@Wih0^T + biases   (W in 256 regs)
//   blocks 16-31: gemm1 (g,s): xw1 = h0@Wih1^T + biases  (W 384 regs + 128KB LDS)
//   blocks 32-35: scan0: 4 waves, wave owns 128 n; W_hh0 400 regs + 112KB LDS
//   blocks 36-39: scan1: same + fused FC partials
// Scan changes vs r9: hbuf double-buffered (stash shrunk to 7/8 nt, nt7 in
// wreg2) -> ONE lgkmcnt+barrier per step; h0 readback post-barrier; chunk
// flags polled with 4 parallel relaxed loads + acquire fence; xv prefetched
// one full step ahead (deferred past the release __syncthreads on L0
// boundary steps so the vmcnt(0) drain doesn't stall it).
// ---------------------------------------------------------------------------

typedef _Float16 half8 __attribute__((ext_vector_type(8)));
typedef _Float16 half4 __attribute__((ext_vector_type(4)));
typedef float    f32x4 __attribute__((ext_vector_type(4)));

#define T_DIM 512
#define H_DIM 512
#define CHUNK 16

#define RAW_BARRIER() asm volatile("s_waitcnt lgkmcnt(0)\n\ts_barrier" ::: "memory")

__global__ __launch_bounds__(256) void conv_w_f16(
    const float* __restrict__ in, _Float16* __restrict__ out)
{
    int i = (blockIdx.x * 256 + threadIdx.x) * 4;
    float4 v = *(const float4*)(in + i);
    out[i + 0] = (_Float16)v.x;
    out[i + 1] = (_Float16)v.y;
    out[i + 2] = (_Float16)v.z;
    out[i + 3] = (_Float16)v.w;
}

__global__ __launch_bounds__(64) void init_flags(int* flags)
{
    flags[threadIdx.x] = 0;
}

// ---------------------------------------------------------------------------
// One fused pipeline kernel. LDS map (halfs), per-block usage:
//   gemm1: [0, 65536)  W-stash, per-wave: w*16384 + ((kt4*8+nt)*64+lane)*8
//   scan:  [0, 57344)  W-stash, per-wave: w*14336 + ((kt4*7+nt)*64+lane)*8
//          [57344, 73984)  hbuf[2][16][520]  (double-buffered)
// ---------------------------------------------------------------------------
#define WSTASH 0
#define HBUF   57344
#define HBUFSZ 8320   // 16 rows * 520 halfs

__global__ __launch_bounds__(256, 1) void pipeline(
    const float* __restrict__ x,       // [64][512][256] fp32
    const float* __restrict__ Wih0,    // [512][256] fp32
    const float* __restrict__ bih0,
    const float* __restrict__ bhh0,
    const float* __restrict__ Wih1,    // [512][512] fp32
    const float* __restrict__ bih1,
    const float* __restrict__ bhh1,
    const _Float16* __restrict__ W16_0,// [512][512] fp16 (W_hh0)
    const _Float16* __restrict__ W16_1,// [512][512] fp16 (W_hh1)
    const float* __restrict__ wfc,     // [512] fp32
    _Float16* __restrict__ xwF0,       // frag-packed [t][g][8192]
    _Float16* __restrict__ xwF1,       // frag-packed [t][g][8192]
    _Float16* __restrict__ h0,         // [g][t][m][512] fp16
    float* __restrict__ part,          // [16][512][16] fp32
    int* __restrict__ flags)           // [0..15] xw0, [16..19] h0, [20..35] xw1
{
    __shared__ _Float16 smem[73984];   // 147,968 B

    const int bx   = blockIdx.x;
    const int tid  = threadIdx.x;
    const int w    = tid >> 6;    // wave 0..3
    const int lane = tid & 63;
    const int col  = lane & 15;
    const int q    = lane >> 4;

    int* flag_xw0 = flags;        // [16] (g*4+s)
    int* flag_h0  = flags + 16;   // [4]
    int* flag_xw1 = flags + 20;   // [16] (g*4+s)

    // =======================================================================
    if (bx < 16) {
        // -------- gemm0: xw0[t][m][n] = x[m][:]·Wih0[n][:] + biases --------
        const int g = bx >> 2, s = bx & 3;

        half8 wb[8][8];                    // B-frags Wih0, 256 regs
        float bias[8];
#pragma unroll
        for (int nt = 0; nt < 8; ++nt) {
            int n = w * 128 + nt * 16 + col;
            bias[nt] = bih0[n] + bhh0[n];
#pragma unroll
            for (int kt = 0; kt < 8; ++kt) {
                const float* p = Wih0 + (size_t)n * 256 + kt * 32 + q * 8;
                float4 f0 = *(const float4*)p;
                float4 f1 = *(const float4*)(p + 4);
                half8 hv;
                hv[0]=(_Float16)f0.x; hv[1]=(_Float16)f0.y;
                hv[2]=(_Float16)f0.z; hv[3]=(_Float16)f0.w;
                hv[4]=(_Float16)f1.x; hv[5]=(_Float16)f1.y;
                hv[6]=(_Float16)f1.z; hv[7]=(_Float16)f1.w;
                wb[kt][nt] = hv;
            }
        }

        for (int c = 0; c < T_DIM / CHUNK; ++c) {
#pragma unroll
            for (int i = 0; i < 4; ++i) {
                int t = c * CHUNK + s * 4 + i;
                f32x4 acc[8] = {};
#pragma unroll
                for (int kt = 0; kt < 8; ++kt) {
                    const float* p = x + ((size_t)(g * 16 + col) * T_DIM + t) * 256
                                       + kt * 32 + q * 8;
                    float4 a0 = *(const float4*)p;
                    float4 a1 = *(const float4*)(p + 4);
                    half8 ah;
                    ah[0]=(_Float16)a0.x; ah[1]=(_Float16)a0.y;
                    ah[2]=(_Float16)a0.z; ah[3]=(_Float16)a0.w;
                    ah[4]=(_Float16)a1.x; ah[5]=(_Float16)a1.y;
                    ah[6]=(_Float16)a1.z; ah[7]=(_Float16)a1.w;
#pragma unroll
                    for (int nt = 0; nt < 8; ++nt)
                        acc[nt] = __builtin_amdgcn_mfma_f32_16x16x32_f16(
                            ah, wb[kt][nt], acc[nt], 0, 0, 0);
                }
                _Float16* dst = xwF0 + ((size_t)t * 4 + g) * 8192 + lane * 4;
#pragma unroll
                for (int nt = 0; nt < 8; ++nt) {
                    half4 hv;
#pragma unroll
                    for (int r = 0; r < 4; ++r)
                        hv[r] = (_Float16)(acc[nt][r] + bias[nt]);
                    *(half4*)(dst + (w * 8 + nt) * 256) = hv;
                }
            }
            __syncthreads();   // full drain: xw0 chunk stores visible
            if (tid == 0)
                __hip_atomic_store(&flag_xw0[g * 4 + s], c + 1, __ATOMIC_RELEASE,
                                   __HIP_MEMORY_SCOPE_AGENT);
        }
        return;
    }

    // =======================================================================
    if (bx < 32) {
        // -------- gemm1: xw1 = h0 @ Wih1^T + biases --------
        const int g = (bx - 16) >> 2, s = (bx - 16) & 3;

        half8 wb[12][8];                   // B-frags kt 0..11, 384 regs
        float bias[8];
#pragma unroll
        for (int nt = 0; nt < 8; ++nt) {
            int n = w * 128 + nt * 16 + col;
            bias[nt] = bih1[n] + bhh1[n];
#pragma unroll
            for (int kt = 0; kt < 16; ++kt) {
                const float* p = Wih1 + (size_t)n * 512 + kt * 32 + q * 8;
                float4 f0 = *(const float4*)p;
                float4 f1 = *(const float4*)(p + 4);
                half8 hv;
                hv[0]=(_Float16)f0.x; hv[1]=(_Float16)f0.y;
                hv[2]=(_Float16)f0.z; hv[3]=(_Float16)f0.w;
                hv[4]=(_Float16)f1.x; hv[5]=(_Float16)f1.y;
                hv[6]=(_Float16)f1.z; hv[7]=(_Float16)f1.w;
                if (kt < 12) wb[kt][nt] = hv;
                else *(half8*)&smem[WSTASH + w * 16384
                                    + (((kt - 12) * 8 + nt) * 64 + lane) * 8] = hv;
            }
        }
        __syncthreads();

        for (int c = 0; c < T_DIM / CHUNK; ++c) {
            while (__hip_atomic_load(&flag_h0[g], __ATOMIC_ACQUIRE,
                                     __HIP_MEMORY_SCOPE_AGENT) < c + 1)
                __builtin_amdgcn_s_sleep(2);
#pragma unroll
            for (int i = 0; i < 4; ++i) {
                int t = c * CHUNK + s * 4 + i;
                f32x4 acc[8] = {};
#pragma unroll
                for (int kt = 0; kt < 16; ++kt) {
                    half8 ah = *(const half8*)(
                        h0 + ((size_t)(g * T_DIM + t) * 16 + col) * 512
                           + kt * 32 + q * 8);
#pragma unroll
                    for (int nt = 0; nt < 8; ++nt) {
                        half8 b;
                        if (kt < 12) b = wb[kt][nt];
                        else b = *(const half8*)&smem[WSTASH + w * 16384
                                 + (((kt - 12) * 8 + nt) * 64 + lane) * 8];
                        acc[nt] = __builtin_amdgcn_mfma_f32_16x16x32_f16(
                            ah, b, acc[nt], 0, 0, 0);
                    }
                }
                _Float16* dst = xwF1 + ((size_t)t * 4 + g) * 8192 + lane * 4;
#pragma unroll
                for (int nt = 0; nt < 8; ++nt) {
                    half4 hv;
#pragma unroll
                    for (int r = 0; r < 4; ++r)
                        hv[r] = (_Float16)(acc[nt][r] + bias[nt]);
                    *(half4*)(dst + (w * 8 + nt) * 256) = hv;
                }
            }
            __syncthreads();
            if (tid == 0)
                __hip_atomic_store(&flag_xw1[g * 4 + s], c + 1, __ATOMIC_RELEASE,
                                   __HIP_MEMORY_SCOPE_AGENT);
        }
        return;
    }

    // =======================================================================
    // scan roles: bx 32-35 layer0 (g=bx-32), bx 36-39 layer1 (g=bx-36)
    const bool L0 = (bx < 36);
    const int  g  = L0 ? bx - 32 : bx - 36;
    const _Float16* W16 = L0 ? W16_0 : W16_1;
    const _Float16* xwF = L0 ? xwF0 : xwF1;
    int* waitf = (L0 ? flag_xw0 : flag_xw1) + g * 4;

    // zero both hbuf buffers (h_{-1} = 0)
    for (int i = tid; i < 2 * HBUFSZ; i += 256) smem[HBUF + i] = (_Float16)0.f;

    // W_hh: kt 12..15, nt 0..6 -> per-wave LDS stash (112 KB total);
    //       kt 12..15, nt 7    -> wreg2 (16 regs); kt 0..11 -> wreg (384 regs)
#pragma unroll
    for (int kt4 = 0; kt4 < 4; ++kt4)
#pragma unroll
        for (int nt = 0; nt < 7; ++nt)
            *(half8*)&smem[WSTASH + w * 14336 + ((kt4 * 7 + nt) * 64 + lane) * 8] =
                *(const half8*)(W16 + (size_t)(w * 128 + nt * 16 + col) * 512
                                + (12 + kt4) * 32 + q * 8);
    half8 wreg2[4];
#pragma unroll
    for (int kt4 = 0; kt4 < 4; ++kt4)
        wreg2[kt4] = *(const half8*)(W16 + (size_t)(w * 128 + 7 * 16 + col) * 512
                                     + (12 + kt4) * 32 + q * 8);
    half8 wreg[12][8];
#pragma unroll
    for (int kt = 0; kt < 12; ++kt)
#pragma unroll
        for (int nt = 0; nt < 8; ++nt)
            wreg[kt][nt] = *(const half8*)(
                W16 + (size_t)(w * 128 + nt * 16 + col) * 512 + kt * 32 + q * 8);

    float wfn[8] = {};
    if (!L0) {
#pragma unroll
        for (int nt = 0; nt < 8; ++nt) wfn[nt] = wfc[w * 128 + nt * 16 + col];
    }

    __syncthreads();

    // chunk wait: 4 parallel relaxed loads (one round trip) + acquire fence
    auto wait4 = [&](int need) {
        for (;;) {
            int a0 = __hip_atomic_load(waitf + 0, __ATOMIC_RELAXED, __HIP_MEMORY_SCOPE_AGENT);
            int a1 = __hip_atomic_load(waitf + 1, __ATOMIC_RELAXED, __HIP_MEMORY_SCOPE_AGENT);
            int a2 = __hip_atomic_load(waitf + 2, __ATOMIC_RELAXED, __HIP_MEMORY_SCOPE_AGENT);
            int a3 = __hip_atomic_load(waitf + 3, __ATOMIC_RELAXED, __HIP_MEMORY_SCOPE_AGENT);
            if (a0 >= need && a1 >= need && a2 >= need && a3 >= need) break;
            __builtin_amdgcn_s_sleep(2);
        }
        __builtin_amdgcn_fence(__ATOMIC_ACQUIRE, "agent");
    };

    // prologue: chunk 0 ready, prefetch xv(0)
    wait4(1);
    half4 xv[8];
    {
        const _Float16* xwp = xwF + (size_t)g * 8192 + lane * 4;
#pragma unroll
        for (int nt = 0; nt < 8; ++nt)
            xv[nt] = *(const half4*)(xwp + (w * 8 + nt) * 256);
    }

    for (int t = 0; t < T_DIM; ++t) {
        const int HR = HBUF + (t & 1) * HBUFSZ;          // read  h_{t-1}
        const int HW = HBUF + ((t & 1) ^ 1) * HBUFSZ;    // write h_t

        f32x4 acc[8] = {};
#pragma unroll
        for (int kt = 0; kt < 16; ++kt) {
            half8 a = *(const half8*)&smem[HR + col * 520 + kt * 32 + q * 8];
#pragma unroll
            for (int nt = 0; nt < 8; ++nt) {
                half8 b;
                if (kt < 12)     b = wreg[kt][nt];
                else if (nt < 7) b = *(const half8*)&smem[WSTASH + w * 14336
                                     + (((kt - 12) * 7 + nt) * 64 + lane) * 8];
                else             b = wreg2[kt - 12];
                acc[nt] = __builtin_amdgcn_mfma_f32_16x16x32_f16(a, b, acc[nt], 0, 0, 0);
            }
        }

        // h_t = relu(acc+xw) -> other buffer (no WAR: readers use HR).
        float p0 = 0.f, p1 = 0.f, p2 = 0.f, p3 = 0.f;
#pragma unroll
        for (int nt = 0; nt < 8; ++nt) {
            int n = w * 128 + nt * 16 + col;
#pragma unroll
            for (int r = 0; r < 4; ++r) {
                float v = fmaxf(acc[nt][r] + (float)xv[nt][r], 0.f);
                smem[HW + (q * 4 + r) * 520 + n] = (_Float16)v;
                if (!L0) {
                    float pv = v * wfn[nt];
                    if (r == 0) p0 += pv; else if (r == 1) p1 += pv;
                    else if (r == 2) p2 += pv; else p3 += pv;
                }
            }
        }
        if (!L0) {
            // reduce partials over col lanes (m = q*4+r fixed per r)
#pragma unroll
            for (int s2 = 1; s2 < 16; s2 <<= 1) {
                p0 += __shfl_xor(p0, s2); p1 += __shfl_xor(p1, s2);
                p2 += __shfl_xor(p2, s2); p3 += __shfl_xor(p3, s2);
            }
            if (col == 0) {
                f32x4 pv = {p0, p1, p2, p3};
                *(f32x4*)(part + ((size_t)(g * 4 + w) * T_DIM + t) * 16 + q * 4) = pv;
            }
        }

        // next-step chunk wait + xv prefetch (full step of lead). On L0
        // release steps, defer the loads past the __syncthreads vmcnt drain.
        const bool rel = L0 && ((t & (CHUNK - 1)) == CHUNK - 1);
        if (t + 1 < T_DIM) {
            if (((t + 1) & (CHUNK - 1)) == 0) wait4(((t + 1) >> 4) + 1);
            if (!rel) {
                const _Float16* xwp = xwF + ((size_t)(t + 1) * 4 + g) * 8192 + lane * 4;
#pragma unroll
                for (int nt = 0; nt < 8; ++nt)
                    xv[nt] = *(const half4*)(xwp + (w * 8 + nt) * 256);
            }
        }

        RAW_BARRIER();   // single barrier: drains h_t writes AND h_{t-1} reads

        if (L0) {
            // readback h_t (just-written buffer) -> h0 [g][t][m][512]
            int m = w * 4 + q;
#pragma unroll
            for (int seg = 0; seg < 4; ++seg) {
                half8 hv = *(const half8*)&smem[HW + m * 520 + col * 32 + seg * 8];
                *(half8*)(h0 + ((size_t)(g * T_DIM + t) * 16 + m) * 512
                          + col * 32 + seg * 8) = hv;
            }
            if ((t & (CHUNK - 1)) == CHUNK - 1) {
                __syncthreads();   // drain all waves' h0 stores (vmcnt 0)
                if (tid == 0)
                    __hip_atomic_store(&flag_h0[g], (t >> 4) + 1, __ATOMIC_RELEASE,
                                       __HIP_MEMORY_SCOPE_AGENT);
                if (t + 1 < T_DIM) {   // deferred xv prefetch
                    const _Float16* xwp = xwF + ((size_t)(t + 1) * 4 + g) * 8192 + lane * 4;
#pragma unroll
                    for (int nt = 0; nt < 8; ++nt)
                        xv[nt] = *(const half4*)(xwp + (w * 8 + nt) * 256);
                }
            }
        }
    }
}

// ---------------------------------------------------------------------------
__global__ __launch_bounds__(256) void fc_epilogue(
    const float* __restrict__ part, const float* __restrict__ bfc,
    float* __restrict__ outp)
{
    int i = blockIdx.x * 256 + threadIdx.x;   // i = b*512 + t
    int b = i >> 9, t = i & 511;
    int g = b >> 4, m = b & 15;
    float s = bfc[0];
#pragma unroll
    for (int w = 0; w < 4; ++w)
        s += part[((size_t)(g * 4 + w) * T_DIM + t) * 16 + m];
    outp[i] = 1.f / (1.f + __expf(-s));
}

// ---------------------------------------------------------------------------
extern "C" void kernel_launch(void* const* d_in, const int* in_sizes, int n_in,
                              void* d_out, int out_size, void* d_ws, size_t ws_size,
                              hipStream_t stream)
{
    const float* x     = (const float*)d_in[0];
    const float* W_ih0 = (const float*)d_in[1];
    const float* W_hh0 = (const float*)d_in[2];
    const float* b_ih0 = (const float*)d_in[3];
    const float* b_hh0 = (const float*)d_in[4];
    const float* W_ih1 = (const float*)d_in[5];
    const float* W_hh1 = (const float*)d_in[6];
    const float* b_ih1 = (const float*)d_in[7];
    const float* b_hh1 = (const float*)d_in[8];
    const float* W_fc  = (const float*)d_in[9];
    const float* b_fc  = (const float*)d_in[10];

    _Float16* xwF0  = (_Float16*)d_ws;                          // 33.5 MB
    _Float16* xwF1  = xwF0 + (size_t)T_DIM * 4 * 8192;          // 33.5 MB
    _Float16* h0    = xwF1 + (size_t)T_DIM * 4 * 8192;          // 33.5 MB
    _Float16* W16_0 = h0 + (size_t)4 * T_DIM * 16 * 512;        // 512 KB
    _Float16* W16_1 = W16_0 + (size_t)H_DIM * H_DIM;            // 512 KB
    float*    partf = (float*)(W16_1 + (size_t)H_DIM * H_DIM);  // 512 KB
    int*      flags = (int*)(partf + (size_t)16 * T_DIM * 16);

    init_flags<<<1, 64, 0, stream>>>(flags);
    conv_w_f16<<<256, 256, 0, stream>>>(W_hh0, W16_0);
    conv_w_f16<<<256, 256, 0, stream>>>(W_hh1, W16_1);

    pipeline<<<40, 256, 0, stream>>>(x, W_ih0, b_ih0, b_hh0,
                                     W_ih1, b_ih1, b_hh1,
                                     W16_0, W16_1, W_fc,
                                     xwF0, xwF1, h0, partf, flags);

    fc_epilogue<<<(64 * T_DIM) / 256, 256, 0, stream>>>(partf, b_fc, (float*)d_out);
}

// Round 4
// 1726.103 us; speedup vs baseline: 1.0498x; 1.0498x over previous
//
#include <hip/hip_runtime.h>

// ---------------------------------------------------------------------------
// 2-layer ReLU RNN (B=64,T=512,I=256,H=512) + FC(512->1) + sigmoid. fp32 I/O.
// Round 13 = EXACT Round-0 base (CHUNK=16, serialized ACQUIRE spins, two
// RAW_BARRIERs, single hbuf, full 8-nt stash) + ONE identity-safe change:
//   conflict-free & 256B-coalesced h0 readback mapping (col*8 + seg*128).
// CHUNK=8 is DEAD (R11/R12 NaN with it; R0 passes without it).
//   blocks  0-15: gemm0 (g,s): xw0 = x@Wih0^T + biases   (W in 256 regs)
//   blocks 16-31: gemm1 (g,s): xw1 = h0@Wih1^T + biases  (W 384 regs + 128KB LDS)
//   blocks 32-35: scan0: 4 waves, wave owns 128 n; W_hh0 384 regs + 128KB LDS
//   blocks 36-39: scan1: same + fused FC partials
// ---------------------------------------------------------------------------

typedef _Float16 half8 __attribute__((ext_vector_type(8)));
typedef _Float16 half4 __attribute__((ext_vector_type(4)));
typedef float    f32x4 __attribute__((ext_vector_type(4)));

#define T_DIM 512
#define H_DIM 512
#define CHUNK 16

#define RAW_BARRIER() asm volatile("s_waitcnt lgkmcnt(0)\n\ts_barrier" ::: "memory")

__global__ __launch_bounds__(256) void conv_w_f16(
    const float* __restrict__ in, _Float16* __restrict__ out)
{
    int i = (blockIdx.x * 256 + threadIdx.x) * 4;
    float4 v = *(const float4*)(in + i);
    out[i + 0] = (_Float16)v.x;
    out[i + 1] = (_Float16)v.y;
    out[i + 2] = (_Float16)v.z;
    out[i + 3] = (_Float16)v.w;
}

__global__ __launch_bounds__(64) void init_flags(int* flags)
{
    flags[threadIdx.x] = 0;
}

// ---------------------------------------------------------------------------
// One fused pipeline kernel. LDS map (halfs):
//   [0, 65536)        W-stash, per-wave: w*16384 + ((kt4*8+nt)*64+lane)*8
//   [65536, 73856)    hbuf[16][520]
// ---------------------------------------------------------------------------
#define WSTASH 0
#define HBUF   65536

__global__ __launch_bounds__(256, 1) void pipeline(
    const float* __restrict__ x,       // [64][512][256] fp32
    const float* __restrict__ Wih0,    // [512][256] fp32
    const float* __restrict__ bih0,
    const float* __restrict__ bhh0,
    const float* __restrict__ Wih1,    // [512][512] fp32
    const float* __restrict__ bih1,
    const float* __restrict__ bhh1,
    const _Float16* __restrict__ W16_0,// [512][512] fp16 (W_hh0)
    const _Float16* __restrict__ W16_1,// [512][512] fp16 (W_hh1)
    const float* __restrict__ wfc,     // [512] fp32
    _Float16* __restrict__ xwF0,       // frag-packed [t][g][8192]
    _Float16* __restrict__ xwF1,       // frag-packed [t][g][8192]
    _Float16* __restrict__ h0,         // [g][t][m][512] fp16
    float* __restrict__ part,          // [16][512][16] fp32
    int* __restrict__ flags)           // [0..15] xw0, [16..19] h0, [20..35] xw1
{
    __shared__ _Float16 smem[73856];   // 147,712 B

    const int bx   = blockIdx.x;
    const int tid  = threadIdx.x;
    const int w    = tid >> 6;    // wave 0..3
    const int lane = tid & 63;
    const int col  = lane & 15;
    const int q    = lane >> 4;

    int* flag_xw0 = flags;        // [16] (g*4+s)
    int* flag_h0  = flags + 16;   // [4]
    int* flag_xw1 = flags + 20;   // [16] (g*4+s)

    // =======================================================================
    if (bx < 16) {
        // -------- gemm0: xw0[t][m][n] = x[m][:]·Wih0[n][:] + biases --------
        const int g = bx >> 2, s = bx & 3;

        half8 wb[8][8];                    // B-frags Wih0, 256 regs
        float bias[8];
#pragma unroll
        for (int nt = 0; nt < 8; ++nt) {
            int n = w * 128 + nt * 16 + col;
            bias[nt] = bih0[n] + bhh0[n];
#pragma unroll
            for (int kt = 0; kt < 8; ++kt) {
                const float* p = Wih0 + (size_t)n * 256 + kt * 32 + q * 8;
                float4 f0 = *(const float4*)p;
                float4 f1 = *(const float4*)(p + 4);
                half8 hv;
                hv[0]=(_Float16)f0.x; hv[1]=(_Float16)f0.y;
                hv[2]=(_Float16)f0.z; hv[3]=(_Float16)f0.w;
                hv[4]=(_Float16)f1.x; hv[5]=(_Float16)f1.y;
                hv[6]=(_Float16)f1.z; hv[7]=(_Float16)f1.w;
                wb[kt][nt] = hv;
            }
        }

        for (int c = 0; c < T_DIM / CHUNK; ++c) {
#pragma unroll
            for (int i = 0; i < 4; ++i) {
                int t = c * CHUNK + s * 4 + i;
                f32x4 acc[8] = {};
#pragma unroll
                for (int kt = 0; kt < 8; ++kt) {
                    const float* p = x + ((size_t)(g * 16 + col) * T_DIM + t) * 256
                                       + kt * 32 + q * 8;
                    float4 a0 = *(const float4*)p;
                    float4 a1 = *(const float4*)(p + 4);
                    half8 ah;
                    ah[0]=(_Float16)a0.x; ah[1]=(_Float16)a0.y;
                    ah[2]=(_Float16)a0.z; ah[3]=(_Float16)a0.w;
                    ah[4]=(_Float16)a1.x; ah[5]=(_Float16)a1.y;
                    ah[6]=(_Float16)a1.z; ah[7]=(_Float16)a1.w;
#pragma unroll
                    for (int nt = 0; nt < 8; ++nt)
                        acc[nt] = __builtin_amdgcn_mfma_f32_16x16x32_f16(
                            ah, wb[kt][nt], acc[nt], 0, 0, 0);
                }
                _Float16* dst = xwF0 + ((size_t)t * 4 + g) * 8192 + lane * 4;
#pragma unroll
                for (int nt = 0; nt < 8; ++nt) {
                    half4 hv;
#pragma unroll
                    for (int r = 0; r < 4; ++r)
                        hv[r] = (_Float16)(acc[nt][r] + bias[nt]);
                    *(half4*)(dst + (w * 8 + nt) * 256) = hv;
                }
            }
            __syncthreads();   // full drain: xw0 chunk stores visible
            if (tid == 0)
                __hip_atomic_store(&flag_xw0[g * 4 + s], c + 1, __ATOMIC_RELEASE,
                                   __HIP_MEMORY_SCOPE_AGENT);
        }
        return;
    }

    // =======================================================================
    if (bx < 32) {
        // -------- gemm1: xw1 = h0 @ Wih1^T + biases --------
        const int g = (bx - 16) >> 2, s = (bx - 16) & 3;

        half8 wb[12][8];                   // B-frags kt 0..11, 384 regs
        float bias[8];
#pragma unroll
        for (int nt = 0; nt < 8; ++nt) {
            int n = w * 128 + nt * 16 + col;
            bias[nt] = bih1[n] + bhh1[n];
#pragma unroll
            for (int kt = 0; kt < 16; ++kt) {
                const float* p = Wih1 + (size_t)n * 512 + kt * 32 + q * 8;
                float4 f0 = *(const float4*)p;
                float4 f1 = *(const float4*)(p + 4);
                half8 hv;
                hv[0]=(_Float16)f0.x; hv[1]=(_Float16)f0.y;
                hv[2]=(_Float16)f0.z; hv[3]=(_Float16)f0.w;
                hv[4]=(_Float16)f1.x; hv[5]=(_Float16)f1.y;
                hv[6]=(_Float16)f1.z; hv[7]=(_Float16)f1.w;
                if (kt < 12) wb[kt][nt] = hv;
                else *(half8*)&smem[WSTASH + w * 16384
                                    + (((kt - 12) * 8 + nt) * 64 + lane) * 8] = hv;
            }
        }
        __syncthreads();

        for (int c = 0; c < T_DIM / CHUNK; ++c) {
            while (__hip_atomic_load(&flag_h0[g], __ATOMIC_ACQUIRE,
                                     __HIP_MEMORY_SCOPE_AGENT) < c + 1)
                __builtin_amdgcn_s_sleep(2);
#pragma unroll
            for (int i = 0; i < 4; ++i) {
                int t = c * CHUNK + s * 4 + i;
                f32x4 acc[8] = {};
#pragma unroll
                for (int kt = 0; kt < 16; ++kt) {
                    half8 ah = *(const half8*)(
                        h0 + ((size_t)(g * T_DIM + t) * 16 + col) * 512
                           + kt * 32 + q * 8);
#pragma unroll
                    for (int nt = 0; nt < 8; ++nt) {
                        half8 b;
                        if (kt < 12) b = wb[kt][nt];
                        else b = *(const half8*)&smem[WSTASH + w * 16384
                                 + (((kt - 12) * 8 + nt) * 64 + lane) * 8];
                        acc[nt] = __builtin_amdgcn_mfma_f32_16x16x32_f16(
                            ah, b, acc[nt], 0, 0, 0);
                    }
                }
                _Float16* dst = xwF1 + ((size_t)t * 4 + g) * 8192 + lane * 4;
#pragma unroll
                for (int nt = 0; nt < 8; ++nt) {
                    half4 hv;
#pragma unroll
                    for (int r = 0; r < 4; ++r)
                        hv[r] = (_Float16)(acc[nt][r] + bias[nt]);
                    *(half4*)(dst + (w * 8 + nt) * 256) = hv;
                }
            }
            __syncthreads();
            if (tid == 0)
                __hip_atomic_store(&flag_xw1[g * 4 + s], c + 1, __ATOMIC_RELEASE,
                                   __HIP_MEMORY_SCOPE_AGENT);
        }
        return;
    }

    // =======================================================================
    // scan roles: bx 32-35 layer0 (g=bx-32), bx 36-39 layer1 (g=bx-36)
    const bool L0 = (bx < 36);
    const int  g  = L0 ? bx - 32 : bx - 36;
    const _Float16* W16 = L0 ? W16_0 : W16_1;
    const _Float16* xwF = L0 ? xwF0 : xwF1;
    int* waitf = L0 ? flag_xw0 : flag_xw1;

    // zero hbuf
    for (int i = tid; i < 16 * 520; i += 256) smem[HBUF + i] = (_Float16)0.f;

    // W_hh: kt 12..15 -> per-wave LDS stash; kt 0..11 -> registers
#pragma unroll
    for (int kt4 = 0; kt4 < 4; ++kt4)
#pragma unroll
        for (int nt = 0; nt < 8; ++nt)
            *(half8*)&smem[WSTASH + w * 16384 + ((kt4 * 8 + nt) * 64 + lane) * 8] =
                *(const half8*)(W16 + (size_t)(w * 128 + nt * 16 + col) * 512
                                + (12 + kt4) * 32 + q * 8);
    half8 wreg[12][8];
#pragma unroll
    for (int kt = 0; kt < 12; ++kt)
#pragma unroll
        for (int nt = 0; nt < 8; ++nt)
            wreg[kt][nt] = *(const half8*)(
                W16 + (size_t)(w * 128 + nt * 16 + col) * 512 + kt * 32 + q * 8);

    float wfn[8] = {};
    if (!L0) {
#pragma unroll
        for (int nt = 0; nt < 8; ++nt) wfn[nt] = wfc[w * 128 + nt * 16 + col];
    }

    __syncthreads();

    for (int t = 0; t < T_DIM; ++t) {
        if ((t & (CHUNK - 1)) == 0) {
            int need = (t >> 4) + 1;
#pragma unroll
            for (int s4 = 0; s4 < 4; ++s4)
                while (__hip_atomic_load(&waitf[g * 4 + s4], __ATOMIC_ACQUIRE,
                                         __HIP_MEMORY_SCOPE_AGENT) < need)
                    __builtin_amdgcn_s_sleep(2);
        }

        // xw loads (frag-packed, 8B/lane coalesced)
        half4 xv[8];
        {
            const _Float16* xwp = xwF + ((size_t)t * 4 + g) * 8192 + lane * 4;
#pragma unroll
            for (int nt = 0; nt < 8; ++nt)
                xv[nt] = *(const half4*)(xwp + (w * 8 + nt) * 256);
        }

        f32x4 acc[8] = {};
#pragma unroll
        for (int kt = 0; kt < 16; ++kt) {
            half8 a = *(const half8*)&smem[HBUF + col * 520 + kt * 32 + q * 8];
#pragma unroll
            for (int nt = 0; nt < 8; ++nt) {
                half8 b;
                if (kt < 12) b = wreg[kt][nt];
                else b = *(const half8*)&smem[WSTASH + w * 16384
                         + (((kt - 12) * 8 + nt) * 64 + lane) * 8];
                acc[nt] = __builtin_amdgcn_mfma_f32_16x16x32_f16(a, b, acc[nt], 0, 0, 0);
            }
        }
        RAW_BARRIER();   // all reads of h_{t-1} done

        // h_t = relu(acc+xw) -> hbuf ; layer1: FC partial in the same pass
        float p0 = 0.f, p1 = 0.f, p2 = 0.f, p3 = 0.f;
#pragma unroll
        for (int nt = 0; nt < 8; ++nt) {
            int n = w * 128 + nt * 16 + col;
#pragma unroll
            for (int r = 0; r < 4; ++r) {
                float v = fmaxf(acc[nt][r] + (float)xv[nt][r], 0.f);
                smem[HBUF + (q * 4 + r) * 520 + n] = (_Float16)v;
                if (!L0) {
                    float pv = v * wfn[nt];
                    if (r == 0) p0 += pv; else if (r == 1) p1 += pv;
                    else if (r == 2) p2 += pv; else p3 += pv;
                }
            }
        }
        RAW_BARRIER();   // h_t visible

        if (L0) {
            // readback hbuf rows -> h0 [g][t][m][512]
            // lane(col,q): m=w*4+q, half-off = col*8 + seg*128  (identity copy,
            // same offset both sides; conflict-free banks, 256B-coalesced
            // global runs per 16 lanes)
            int m = w * 4 + q;
#pragma unroll
            for (int seg = 0; seg < 4; ++seg) {
                half8 hv = *(const half8*)&smem[HBUF + m * 520 + col * 8 + seg * 128];
                *(half8*)(h0 + ((size_t)(g * T_DIM + t) * 16 + m) * 512
                          + col * 8 + seg * 128) = hv;
            }
            if ((t & (CHUNK - 1)) == CHUNK - 1) {
                __syncthreads();   // drain all waves' h0 stores
                if (tid == 0)
                    __hip_atomic_store(&flag_h0[g], (t >> 4) + 1, __ATOMIC_RELEASE,
                                       __HIP_MEMORY_SCOPE_AGENT);
            }
        } else {
            // reduce partials over col lanes (m = q*4+r fixed per r)
#pragma unroll
            for (int s2 = 1; s2 < 16; s2 <<= 1) {
                p0 += __shfl_xor(p0, s2); p1 += __shfl_xor(p1, s2);
                p2 += __shfl_xor(p2, s2); p3 += __shfl_xor(p3, s2);
            }
            if (col == 0) {
                f32x4 pv = {p0, p1, p2, p3};
                *(f32x4*)(part + ((size_t)(g * 4 + w) * T_DIM + t) * 16 + q * 4) = pv;
            }
        }
    }
}

// ---------------------------------------------------------------------------
__global__ __launch_bounds__(256) void fc_epilogue(
    const float* __restrict__ part, const float* __restrict__ bfc,
    float* __restrict__ outp)
{
    int i = blockIdx.x * 256 + threadIdx.x;   // i = b*512 + t
    int b = i >> 9, t = i & 511;
    int g = b >> 4, m = b & 15;
    float s = bfc[0];
#pragma unroll
    for (int w = 0; w < 4; ++w)
        s += part[((size_t)(g * 4 + w) * T_DIM + t) * 16 + m];
    outp[i] = 1.f / (1.f + __expf(-s));
}

// ---------------------------------------------------------------------------
extern "C" void kernel_launch(void* const* d_in, const int* in_sizes, int n_in,
                              void* d_out, int out_size, void* d_ws, size_t ws_size,
                              hipStream_t stream)
{
    const float* x     = (const float*)d_in[0];
    const float* W_ih0 = (const float*)d_in[1];
    const float* W_hh0 = (const float*)d_in[2];
    const float* b_ih0 = (const float*)d_in[3];
    const float* b_hh0 = (const float*)d_in[4];
    const float* W_ih1 = (const float*)d_in[5];
    const float* W_hh1 = (const float*)d_in[6];
    const float* b_ih1 = (const float*)d_in[7];
    const float* b_hh1 = (const float*)d_in[8];
    const float* W_fc  = (const float*)d_in[9];
    const float* b_fc  = (const float*)d_in[10];

    _Float16* xwF0  = (_Float16*)d_ws;                          // 33.5 MB
    _Float16* xwF1  = xwF0 + (size_t)T_DIM * 4 * 8192;          // 33.5 MB
    _Float16* h0    = xwF1 + (size_t)T_DIM * 4 * 8192;          // 33.5 MB
    _Float16* W16_0 = h0 + (size_t)4 * T_DIM * 16 * 512;        // 512 KB
    _Float16* W16_1 = W16_0 + (size_t)H_DIM * H_DIM;            // 512 KB
    float*    partf = (float*)(W16_1 + (size_t)H_DIM * H_DIM);  // 512 KB
    int*      flags = (int*)(partf + (size_t)16 * T_DIM * 16);

    init_flags<<<1, 64, 0, stream>>>(flags);
    conv_w_f16<<<256, 256, 0, stream>>>(W_hh0, W16_0);
    conv_w_f16<<<256, 256, 0, stream>>>(W_hh1, W16_1);

    pipeline<<<40, 256, 0, stream>>>(x, W_ih0, b_ih0, b_hh0,
                                     W_ih1, b_ih1, b_hh1,
                                     W16_0, W16_1, W_fc,
                                     xwF0, xwF1, h0, partf, flags);

    fc_epilogue<<<(64 * T_DIM) / 256, 256, 0, stream>>>(partf, b_fc, (float*)d_out);
}